// Round 2
// baseline (1652.995 us; speedup 1.0000x reference)
//
#include <hip/hip_runtime.h>
#include <hip/hip_bf16.h>
#include <cstdint>

// Fused LISTA: each block owns 64 batch rows and runs init + all 16 steps.
// Z tile lives in LDS (bf16, XOR-swizzled 16B chunks, verified 0-conflict in R1).
// B = X@We^T lives in registers (bf16x2-packed, C-layout). S fragments are
// loaded directly from global (L2-resident) — no K-loop barriers.

typedef __attribute__((ext_vector_type(8))) short short8;   // 8 x bf16
typedef __attribute__((ext_vector_type(4))) float floatx4;  // mfma acc

__device__ __forceinline__ unsigned short f2b(float f) {
    __hip_bfloat16 h = __float2bfloat16(f);
    return *(unsigned short*)&h;
}
__device__ __forceinline__ float b2f(unsigned short u) {
    union { unsigned int i; float f; } x; x.i = ((unsigned int)u) << 16; return x.f;
}

__global__ void __launch_bounds__(512, 2)
lista_fused(const unsigned short* __restrict__ Xbf,   // 16384 x 256
            const unsigned short* __restrict__ Webf,  // 1024 x 256
            const unsigned short* __restrict__ Sbf,   // 1024 x 1024
            const float* __restrict__ theta,          // 1024
            float* __restrict__ out)                  // 16384 x 1024 fp32
{
    __shared__ __align__(16) unsigned short Zd[64 * 1024];  // 128 KB

    const int t    = threadIdx.x;
    const int wave = t >> 6;        // 0..7, owns cols [wave*128, wave*128+128)
    const int lane = t & 63;
    const int l15  = lane & 15;
    const int q    = lane >> 4;     // k-quad / row-quad
    const int blk  = blockIdx.x;    // 0..255, owns rows [blk*64, blk*64+64)

    floatx4 acc[4][8];              // 128 VGPR: 64 rows x 128 cols
    unsigned int Bpk[4][8][2];      // 64 VGPR: B tile, bf16x2 packed (v-pairs)

    // per-lane base byte offsets (A/B fragment layout: lane -> 16B at
    //   A[m=l15][k=q*8..q*8+7],  B[n=l15][k=q*8..q*8+7])
    const char* Sb = (const char*)Sbf  + ((size_t)(wave * 128 + l15) * 1024 + q * 8) * 2;
    const char* Xb = (const char*)Xbf  + ((size_t)(blk * 64   + l15) * 256  + q * 8) * 2;
    const char* Wb = (const char*)Webf + ((size_t)(wave * 128 + l15) * 256  + q * 8) * 2;

#pragma unroll
    for (int mi = 0; mi < 4; ++mi)
#pragma unroll
        for (int ni = 0; ni < 8; ++ni) acc[mi][ni] = (floatx4){0.f, 0.f, 0.f, 0.f};

    // ---- init GEMM: acc = X @ We^T  (K = 256, frags direct from global) ----
#pragma unroll
    for (int kc = 0; kc < 8; ++kc) {
        short8 af[4];
#pragma unroll
        for (int mi = 0; mi < 4; ++mi)
            af[mi] = *(const short8*)(Xb + mi * 8192 + kc * 64);   // 16 rows * 512 B
#pragma unroll
        for (int h = 0; h < 2; ++h) {
            short8 sf[4];
#pragma unroll
            for (int j = 0; j < 4; ++j)
                sf[j] = *(const short8*)(Wb + (h * 4 + j) * 8192 + kc * 64);
#pragma unroll
            for (int mi = 0; mi < 4; ++mi)
#pragma unroll
                for (int j = 0; j < 4; ++j)
                    acc[mi][h * 4 + j] = __builtin_amdgcn_mfma_f32_16x16x32_bf16(
                        af[mi], sf[j], acc[mi][h * 4 + j], 0, 0, 0);
        }
    }

    // ---- init epilogue: Bpk = pack(acc); Z0 = eta(B) -> LDS; acc = B ----
#pragma unroll
    for (int mi = 0; mi < 4; ++mi) {
#pragma unroll
        for (int ni = 0; ni < 8; ++ni) {
            const int col   = wave * 128 + ni * 16 + l15;
            const float th  = theta[col];
            const int chunk = col >> 3;
            const int coff  = (col & 7) * 2;
#pragma unroll
            for (int vp = 0; vp < 2; ++vp) {
                const float c0 = acc[mi][ni][vp * 2 + 0];
                const float c1 = acc[mi][ni][vp * 2 + 1];
                const unsigned short b0 = f2b(c0), b1 = f2b(c1);
                Bpk[mi][ni][vp] = (unsigned int)b0 | ((unsigned int)b1 << 16);
                const float a0 = fabsf(c0) - th, a1 = fabsf(c1) - th;
                const float z0 = a0 > 0.f ? copysignf(a0, c0) : 0.f;
                const float z1 = a1 > 0.f ? copysignf(a1, c1) : 0.f;
                const int r0 = mi * 16 + q * 4 + vp * 2;
                const int r1 = r0 + 1;
                const int s0 = (chunk & ~7) | ((chunk ^ r0) & 7);
                const int s1 = (chunk & ~7) | ((chunk ^ r1) & 7);
                *(unsigned short*)((char*)Zd + r0 * 2048 + s0 * 16 + coff) = f2b(z0);
                *(unsigned short*)((char*)Zd + r1 * 2048 + s1 * 16 + coff) = f2b(z1);
                acc[mi][ni][vp * 2 + 0] = b2f(b0);   // acc := B (rounded, consistent)
                acc[mi][ni][vp * 2 + 1] = b2f(b1);
            }
        }
    }
    __syncthreads();

    // ---- 16 fused steps ----
#pragma unroll 1
    for (int step = 1; step <= 16; ++step) {
        // K-loop: acc += Z @ S^T  (Z from LDS, S frags direct from global/L2)
        for (int kc = 0; kc < 32; ++kc) {
            short8 af[4];
#pragma unroll
            for (int mi = 0; mi < 4; ++mi) {
                const int row = mi * 16 + l15;
                const int c   = kc * 4 + q;
                const int s   = (c & ~7) | ((c ^ row) & 7);
                af[mi] = *(const short8*)((const char*)Zd + row * 2048 + s * 16);
            }
#pragma unroll
            for (int h = 0; h < 2; ++h) {
                short8 sf[4];
#pragma unroll
                for (int j = 0; j < 4; ++j)
                    sf[j] = *(const short8*)(Sb + (h * 4 + j) * 32768 + kc * 64);
#pragma unroll
                for (int mi = 0; mi < 4; ++mi)
#pragma unroll
                    for (int j = 0; j < 4; ++j)
                        acc[mi][h * 4 + j] = __builtin_amdgcn_mfma_f32_16x16x32_bf16(
                            af[mi], sf[j], acc[mi][h * 4 + j], 0, 0, 0);
            }
        }
        __syncthreads();   // all waves done reading old Z

        if (step < 16) {
            // epilogue: z = eta(acc); Z <- z (LDS); acc := B
#pragma unroll
            for (int mi = 0; mi < 4; ++mi) {
#pragma unroll
                for (int ni = 0; ni < 8; ++ni) {
                    const int col   = wave * 128 + ni * 16 + l15;
                    const float th  = theta[col];
                    const int chunk = col >> 3;
                    const int coff  = (col & 7) * 2;
#pragma unroll
                    for (int v = 0; v < 4; ++v) {
                        const float c = acc[mi][ni][v];
                        const float a = fabsf(c) - th;
                        const float z = a > 0.f ? copysignf(a, c) : 0.f;
                        const int r = mi * 16 + q * 4 + v;
                        const int s = (chunk & ~7) | ((chunk ^ r) & 7);
                        *(unsigned short*)((char*)Zd + r * 2048 + s * 16 + coff) = f2b(z);
                        const unsigned int bp = Bpk[mi][ni][v >> 1];
                        acc[mi][ni][v] = b2f((v & 1) ? (unsigned short)(bp >> 16)
                                                     : (unsigned short)(bp & 0xffff));
                    }
                }
            }
            __syncthreads();   // new Z visible before next step reads
        } else {
            // final epilogue: out = eta(acc), fp32
#pragma unroll
            for (int mi = 0; mi < 4; ++mi) {
#pragma unroll
                for (int ni = 0; ni < 8; ++ni) {
                    const int col  = wave * 128 + ni * 16 + l15;
                    const float th = theta[col];
#pragma unroll
                    for (int v = 0; v < 4; ++v) {
                        const float c = acc[mi][ni][v];
                        const float a = fabsf(c) - th;
                        const float z = a > 0.f ? copysignf(a, c) : 0.f;
                        const int r = mi * 16 + q * 4 + v;
                        out[(size_t)(blk * 64 + r) * 1024 + col] = z;
                    }
                }
            }
        }
    }
}

__global__ void __launch_bounds__(256)
cvt4(const float* __restrict__ s, unsigned short* __restrict__ d, int n4)
{
    const int i = blockIdx.x * blockDim.x + threadIdx.x;
    if (i < n4) {
        const float4 v = ((const float4*)s)[i];
        ushort4 o;
        o.x = f2b(v.x); o.y = f2b(v.y); o.z = f2b(v.z); o.w = f2b(v.w);
        ((ushort4*)d)[i] = o;
    }
}

extern "C" void kernel_launch(void* const* d_in, const int* in_sizes, int n_in,
                              void* d_out, int out_size, void* d_ws, size_t ws_size,
                              hipStream_t stream) {
    const float* X     = (const float*)d_in[0];  // 16384 x 256
    const float* We    = (const float*)d_in[1];  // 1024 x 256
    const float* S     = (const float*)d_in[2];  // 1024 x 1024
    const float* theta = (const float*)d_in[3];  // 1024
    float* out = (float*)d_out;                  // 16384 x 1024 fp32

    char* ws = (char*)d_ws;
    unsigned short* S_bf  = (unsigned short*)(ws);                           // 2 MB
    unsigned short* X_bf  = (unsigned short*)(ws + (size_t)2  * 1048576);    // 8 MB
    unsigned short* We_bf = (unsigned short*)(ws + (size_t)10 * 1048576);    // 0.5 MB

    cvt4<<<dim3(1024), dim3(256), 0, stream>>>(S,  S_bf,  1024 * 1024 / 4);
    cvt4<<<dim3(4096), dim3(256), 0, stream>>>(X,  X_bf,  16384 * 256 / 4);
    cvt4<<<dim3(256),  dim3(256), 0, stream>>>(We, We_bf, 1024 * 256 / 4);

    lista_fused<<<dim3(256), dim3(512), 0, stream>>>(X_bf, We_bf, S_bf, theta, out);
}